// Round 1
// baseline (597.037 us; speedup 1.0000x reference)
//
#include <hip/hip_runtime.h>

#define DD 128   // feature dim
#define DH 64    // float2 per row

// ---------------- row_ptr via binary search on sorted edge_row ----------------
__global__ __launch_bounds__(256) void k_row_ptr(const int* __restrict__ row,
                                                 int* __restrict__ rp, int n, int e) {
    int i = blockIdx.x * 256 + threadIdx.x;
    if (i > n) return;
    int lo = 0, hi = e;
    while (lo < hi) { int m = (lo + hi) >> 1; if (row[m] < i) lo = m + 1; else hi = m; }
    rp[i] = lo;
}

// ---------------- transpose W1,W2 into workspace (WT[k][j] = W[j][k]) ----------------
__global__ __launch_bounds__(256) void k_transpose_w(const float* __restrict__ W1,
                                                     const float* __restrict__ W2,
                                                     float* __restrict__ WT1,
                                                     float* __restrict__ WT2) {
    int id = blockIdx.x * 256 + threadIdx.x;   // 0..32767
    int m = id >> 14;
    int r = id & 16383;
    int k = r >> 7, j = r & 127;
    if (m == 0) WT1[k * DD + j] = W1[j * DD + k];
    else        WT2[k * DD + j] = W2[j * DD + k];
}

// ---------------- SpMM: one wave per row, lane owns float2 ----------------
// PASS 1: out1 = L1x = Lx + diag*feat ; out2 = inter = Lx*feat
// PASS 2: out1 = Linter = L @ inter
template <int PASS>
__global__ __launch_bounds__(256) void k_spmm(const int* __restrict__ col,
                                              const float* __restrict__ val,
                                              const float* __restrict__ xin,
                                              const int* __restrict__ rp,
                                              const float* __restrict__ feat,
                                              const float* __restrict__ diag,
                                              float* __restrict__ out1,
                                              float* __restrict__ out2, int n) {
    int lane = threadIdx.x & 63;
    int row = blockIdx.x * 4 + (threadIdx.x >> 6);
    if (row >= n) return;
    row = __builtin_amdgcn_readfirstlane(row);  // wave-uniform -> scalar loads
    int s = rp[row], eend = rp[row + 1];
    const float2* x2 = (const float2*)xin;
    float ax = 0.f, ay = 0.f;
    int e = s;
    for (; e + 4 <= eend; e += 4) {
        int c0 = col[e], c1 = col[e + 1], c2 = col[e + 2], c3 = col[e + 3];
        float v0 = val[e], v1 = val[e + 1], v2 = val[e + 2], v3 = val[e + 3];
        float2 g0 = x2[c0 * DH + lane];
        float2 g1 = x2[c1 * DH + lane];
        float2 g2 = x2[c2 * DH + lane];
        float2 g3 = x2[c3 * DH + lane];
        ax = fmaf(v0, g0.x, ax); ay = fmaf(v0, g0.y, ay);
        ax = fmaf(v1, g1.x, ax); ay = fmaf(v1, g1.y, ay);
        ax = fmaf(v2, g2.x, ax); ay = fmaf(v2, g2.y, ay);
        ax = fmaf(v3, g3.x, ax); ay = fmaf(v3, g3.y, ay);
    }
    for (; e < eend; ++e) {
        int c = col[e]; float v = val[e];
        float2 g = x2[c * DH + lane];
        ax = fmaf(v, g.x, ax); ay = fmaf(v, g.y, ay);
    }
    if (PASS == 1) {
        float dg = diag[row];
        float2 f = ((const float2*)feat)[row * DH + lane];
        float2 l1; l1.x = fmaf(dg, f.x, ax); l1.y = fmaf(dg, f.y, ay);
        float2 it; it.x = ax * f.x; it.y = ay * f.y;
        ((float2*)out1)[row * DH + lane] = l1;
        ((float2*)out2)[row * DH + lane] = it;
    } else {
        float2 o; o.x = ax; o.y = ay;
        ((float2*)out1)[row * DH + lane] = o;
    }
}

// ---------------- fused dual GEMM: out = A@W1^T + B@W2^T + b1 + b2 ----------------
// block = 256 threads, 64 rows per block; W chunks + A/B tiles staged in LDS.
#define FMA4(ACC, S, W)                                   \
    ACC.x = fmaf(S, W.x, ACC.x); ACC.y = fmaf(S, W.y, ACC.y); \
    ACC.z = fmaf(S, W.z, ACC.z); ACC.w = fmaf(S, W.w, ACC.w);

__global__ __launch_bounds__(256) void k_gemm(const float* __restrict__ A,
                                              const float* __restrict__ B,
                                              const float* __restrict__ WT1,
                                              const float* __restrict__ WT2,
                                              const float* __restrict__ b1,
                                              const float* __restrict__ b2,
                                              float* __restrict__ out, int n) {
    __shared__ __align__(16) float Wls1[32][132];
    __shared__ __align__(16) float Wls2[32][132];
    __shared__ __align__(16) float Als[64][32];
    __shared__ __align__(16) float Bls[64][32];
    int t = threadIdx.x;
    int rowbase = blockIdx.x * 64;
    int j4 = (t & 31) * 4;
    int g = t >> 5;  // 0..7
    float4 acc[8];
#pragma unroll
    for (int i = 0; i < 8; ++i) acc[i] = make_float4(0.f, 0.f, 0.f, 0.f);

    for (int kc = 0; kc < DD; kc += 32) {
        __syncthreads();
        // stage W chunks: 32x128 each
#pragma unroll
        for (int u = 0; u < 16; ++u) {
            int id = u * 256 + t;       // 0..4095
            int kk = id >> 7, j = id & 127;
            Wls1[kk][j] = WT1[(kc + kk) * DD + j];
            Wls2[kk][j] = WT2[(kc + kk) * DD + j];
        }
        // stage A/B tiles: 64x32
#pragma unroll
        for (int u = 0; u < 8; ++u) {
            int id = u * 256 + t;       // 0..2047
            int r = id >> 5, kk = id & 31;
            int gr = rowbase + r; if (gr >= n) gr = n - 1;
            Als[r][kk] = A[(size_t)gr * DD + kc + kk];
            Bls[r][kk] = B[(size_t)gr * DD + kc + kk];
        }
        __syncthreads();
#pragma unroll
        for (int kk4 = 0; kk4 < 8; ++kk4) {
            float4 w1[4], w2[4];
#pragma unroll
            for (int u2 = 0; u2 < 4; ++u2) {
                w1[u2] = *(const float4*)&Wls1[kk4 * 4 + u2][j4];
                w2[u2] = *(const float4*)&Wls2[kk4 * 4 + u2][j4];
            }
#pragma unroll
            for (int r8 = 0; r8 < 8; ++r8) {
                float4 a = *(const float4*)&Als[g + 8 * r8][kk4 * 4];
                float4 b = *(const float4*)&Bls[g + 8 * r8][kk4 * 4];
                FMA4(acc[r8], a.x, w1[0]); FMA4(acc[r8], a.y, w1[1]);
                FMA4(acc[r8], a.z, w1[2]); FMA4(acc[r8], a.w, w1[3]);
                FMA4(acc[r8], b.x, w2[0]); FMA4(acc[r8], b.y, w2[1]);
                FMA4(acc[r8], b.z, w2[2]); FMA4(acc[r8], b.w, w2[3]);
            }
        }
    }
    float4 bb1 = *(const float4*)&b1[j4];
    float4 bb2 = *(const float4*)&b2[j4];
    float bx = bb1.x + bb2.x, by = bb1.y + bb2.y, bz = bb1.z + bb2.z, bw = bb1.w + bb2.w;
#pragma unroll
    for (int r8 = 0; r8 < 8; ++r8) {
        int gr = rowbase + g + 8 * r8;
        if (gr < n) {
            float4 o;
            o.x = acc[r8].x + bx; o.y = acc[r8].y + by;
            o.z = acc[r8].z + bz; o.w = acc[r8].w + bw;
            *(float4*)&out[(size_t)gr * DD + j4] = o;
        }
    }
}

extern "C" void kernel_launch(void* const* d_in, const int* in_sizes, int n_in,
                              void* d_out, int out_size, void* d_ws, size_t ws_size,
                              hipStream_t stream) {
    const int*   edge_row = (const int*)d_in[0];
    const int*   edge_col = (const int*)d_in[1];
    const float* edge_val = (const float*)d_in[2];
    const float* diag     = (const float*)d_in[3];
    const float* feat     = (const float*)d_in[4];
    const float* W1       = (const float*)d_in[5];
    const float* b1       = (const float*)d_in[6];
    const float* W2       = (const float*)d_in[7];
    const float* b2       = (const float*)d_in[8];
    float* out = (float*)d_out;

    const int E = in_sizes[0];
    const int N = in_sizes[3];

    // workspace layout
    char* ws = (char*)d_ws;
    size_t off = 0;
    int* rp = (int*)(ws + off);            off += (((size_t)(N + 1) * 4) + 255) & ~(size_t)255;
    float* L1x    = (float*)(ws + off);    off += (size_t)N * DD * 4;
    float* inter  = (float*)(ws + off);    off += (size_t)N * DD * 4;
    float* Linter = (float*)(ws + off);    off += (size_t)N * DD * 4;
    float* WT1    = (float*)(ws + off);    off += (size_t)DD * DD * 4;
    float* WT2    = (float*)(ws + off);    off += (size_t)DD * DD * 4;
    (void)ws_size; (void)n_in; (void)out_size;

    // 1. row_ptr
    k_row_ptr<<<(N + 1 + 255) / 256, 256, 0, stream>>>(edge_row, rp, N, E);
    // 2. transpose weights
    k_transpose_w<<<128, 256, 0, stream>>>(W1, W2, WT1, WT2);
    // 3. SpMM pass 1: L1x, inter
    k_spmm<1><<<(N + 3) / 4, 256, 0, stream>>>(edge_col, edge_val, feat, rp, feat, diag,
                                               L1x, inter, N);
    // 4. SpMM pass 2: Linter
    k_spmm<2><<<(N + 3) / 4, 256, 0, stream>>>(edge_col, edge_val, inter, rp, nullptr, nullptr,
                                               Linter, nullptr, N);
    // 5. fused dual GEMM + bias
    k_gemm<<<(N + 63) / 64, 256, 0, stream>>>(L1x, Linter, WT1, WT2, b1, b2, out, N);
}

// Round 2
// 375.503 us; speedup vs baseline: 1.5900x; 1.5900x over previous
//
#include <hip/hip_runtime.h>

#define DD 128   // feature dim
#define DH 64    // bf16-pairs (uint) per row

typedef unsigned int uint32;

__device__ __forceinline__ uint32 pack_bf16(float a, float b) {
    uint32 ua = __builtin_bit_cast(uint32, a);
    uint32 ub = __builtin_bit_cast(uint32, b);
    ua = (ua + 0x7fffu + ((ua >> 16) & 1u)) >> 16;   // RNE
    ub = (ub + 0x7fffu + ((ub >> 16) & 1u)) >> 16;
    return ua | (ub << 16);
}

__device__ __forceinline__ float bf_lo(uint32 u) { return __builtin_bit_cast(float, u << 16); }
__device__ __forceinline__ float bf_hi(uint32 u) { return __builtin_bit_cast(float, u & 0xffff0000u); }

// ---------------- row_ptr via binary search on sorted edge_row ----------------
__global__ __launch_bounds__(256) void k_row_ptr(const int* __restrict__ row,
                                                 int* __restrict__ rp, int n, int e) {
    int i = blockIdx.x * 256 + threadIdx.x;
    if (i > n) return;
    int lo = 0, hi = e;
    while (lo < hi) { int m = (lo + hi) >> 1; if (row[m] < i) lo = m + 1; else hi = m; }
    rp[i] = lo;
}

// ---------------- prep: feat -> bf16 pairs; transpose W1,W2 (f32) ----------------
__global__ __launch_bounds__(256) void k_prep(const float* __restrict__ feat,
                                              uint32* __restrict__ featbf,
                                              const float* __restrict__ W1,
                                              const float* __restrict__ W2,
                                              float* __restrict__ WT1,
                                              float* __restrict__ WT2, int n) {
    int id = blockIdx.x * 256 + threadIdx.x;       // over n*32 float4's
    if (id < n * (DD / 4)) {
        float4 f = ((const float4*)feat)[id];
        uint32 p0 = pack_bf16(f.x, f.y);
        uint32 p1 = pack_bf16(f.z, f.w);
        ((uint2*)featbf)[id] = make_uint2(p0, p1);
    }
    if (id < 2 * DD * DD) {                        // 32768 transpose slots
        int m = id >> 14;
        int r = id & 16383;
        int k = r >> 7, j = r & 127;
        if (m == 0) WT1[k * DD + j] = W1[j * DD + k];
        else        WT2[k * DD + j] = W2[j * DD + k];
    }
}

// ---------------- SpMM: one wave per row, lane owns a bf16 pair ----------------
// PASS 1: out1 = L1x = Lx + diag*feat (f32) ; out2 = inter = Lx*feat (bf16)
// PASS 2: out1 = Linter = L @ inter (f32)
template <int PASS>
__global__ __launch_bounds__(256) void k_spmm(const int* __restrict__ col,
                                              const float* __restrict__ val,
                                              const uint32* __restrict__ xbf,
                                              const int* __restrict__ rp,
                                              const uint32* __restrict__ featbf,
                                              const float* __restrict__ diag,
                                              float* __restrict__ out1,
                                              uint32* __restrict__ out2, int n) {
    int lane = threadIdx.x & 63;
    int row = blockIdx.x * 4 + (threadIdx.x >> 6);
    if (row >= n) return;
    row = __builtin_amdgcn_readfirstlane(row);  // wave-uniform -> scalar loads
    int s = rp[row], eend = rp[row + 1];
    float ax = 0.f, ay = 0.f;
    int e = s;
    for (; e + 8 <= eend; e += 8) {
        int c[8]; float v[8]; uint32 g[8];
#pragma unroll
        for (int u = 0; u < 8; ++u) { c[u] = col[e + u]; v[u] = val[e + u]; }
#pragma unroll
        for (int u = 0; u < 8; ++u) { g[u] = xbf[c[u] * DH + lane]; }
#pragma unroll
        for (int u = 0; u < 8; ++u) {
            ax = fmaf(v[u], bf_lo(g[u]), ax);
            ay = fmaf(v[u], bf_hi(g[u]), ay);
        }
    }
    for (; e < eend; ++e) {
        int c = col[e]; float v = val[e];
        uint32 g = xbf[c * DH + lane];
        ax = fmaf(v, bf_lo(g), ax);
        ay = fmaf(v, bf_hi(g), ay);
    }
    if (PASS == 1) {
        float dg = diag[row];
        uint32 fu = featbf[row * DH + lane];
        float fx = bf_lo(fu), fy = bf_hi(fu);
        float2 l1; l1.x = fmaf(dg, fx, ax); l1.y = fmaf(dg, fy, ay);
        ((float2*)out1)[row * DH + lane] = l1;
        out2[row * DH + lane] = pack_bf16(ax * fx, ay * fy);
    } else {
        float2 o; o.x = ax; o.y = ay;
        ((float2*)out1)[row * DH + lane] = o;
    }
}

// ---------------- fused dual GEMM: out = A@W1^T + B@W2^T + b1 + b2 ----------------
#define FMA4(ACC, S, W)                                   \
    ACC.x = fmaf(S, W.x, ACC.x); ACC.y = fmaf(S, W.y, ACC.y); \
    ACC.z = fmaf(S, W.z, ACC.z); ACC.w = fmaf(S, W.w, ACC.w);

__global__ __launch_bounds__(256) void k_gemm(const float* __restrict__ A,
                                              const float* __restrict__ B,
                                              const float* __restrict__ WT1,
                                              const float* __restrict__ WT2,
                                              const float* __restrict__ b1,
                                              const float* __restrict__ b2,
                                              float* __restrict__ out, int n) {
    __shared__ __align__(16) float Wls1[32][132];
    __shared__ __align__(16) float Wls2[32][132];
    __shared__ __align__(16) float Als[64][32];
    __shared__ __align__(16) float Bls[64][32];
    int t = threadIdx.x;
    int rowbase = blockIdx.x * 64;
    int j4 = (t & 31) * 4;
    int g = t >> 5;  // 0..7
    float4 acc[8];
#pragma unroll
    for (int i = 0; i < 8; ++i) acc[i] = make_float4(0.f, 0.f, 0.f, 0.f);

    for (int kc = 0; kc < DD; kc += 32) {
        __syncthreads();
#pragma unroll
        for (int u = 0; u < 16; ++u) {
            int id = u * 256 + t;       // 0..4095
            int kk = id >> 7, j = id & 127;
            Wls1[kk][j] = WT1[(kc + kk) * DD + j];
            Wls2[kk][j] = WT2[(kc + kk) * DD + j];
        }
#pragma unroll
        for (int u = 0; u < 8; ++u) {
            int id = u * 256 + t;       // 0..2047
            int r = id >> 5, kk = id & 31;
            int gr = rowbase + r; if (gr >= n) gr = n - 1;
            Als[r][kk] = A[(size_t)gr * DD + kc + kk];
            Bls[r][kk] = B[(size_t)gr * DD + kc + kk];
        }
        __syncthreads();
#pragma unroll
        for (int kk4 = 0; kk4 < 8; ++kk4) {
            float4 w1[4], w2[4];
#pragma unroll
            for (int u2 = 0; u2 < 4; ++u2) {
                w1[u2] = *(const float4*)&Wls1[kk4 * 4 + u2][j4];
                w2[u2] = *(const float4*)&Wls2[kk4 * 4 + u2][j4];
            }
#pragma unroll
            for (int r8 = 0; r8 < 8; ++r8) {
                float4 a = *(const float4*)&Als[g + 8 * r8][kk4 * 4];
                float4 b = *(const float4*)&Bls[g + 8 * r8][kk4 * 4];
                FMA4(acc[r8], a.x, w1[0]); FMA4(acc[r8], a.y, w1[1]);
                FMA4(acc[r8], a.z, w1[2]); FMA4(acc[r8], a.w, w1[3]);
                FMA4(acc[r8], b.x, w2[0]); FMA4(acc[r8], b.y, w2[1]);
                FMA4(acc[r8], b.z, w2[2]); FMA4(acc[r8], b.w, w2[3]);
            }
        }
    }
    float4 bb1 = *(const float4*)&b1[j4];
    float4 bb2 = *(const float4*)&b2[j4];
    float bx = bb1.x + bb2.x, by = bb1.y + bb2.y, bz = bb1.z + bb2.z, bw = bb1.w + bb2.w;
#pragma unroll
    for (int r8 = 0; r8 < 8; ++r8) {
        int gr = rowbase + g + 8 * r8;
        if (gr < n) {
            float4 o;
            o.x = acc[r8].x + bx; o.y = acc[r8].y + by;
            o.z = acc[r8].z + bz; o.w = acc[r8].w + bw;
            *(float4*)&out[(size_t)gr * DD + j4] = o;
        }
    }
}

extern "C" void kernel_launch(void* const* d_in, const int* in_sizes, int n_in,
                              void* d_out, int out_size, void* d_ws, size_t ws_size,
                              hipStream_t stream) {
    const int*   edge_row = (const int*)d_in[0];
    const int*   edge_col = (const int*)d_in[1];
    const float* edge_val = (const float*)d_in[2];
    const float* diag     = (const float*)d_in[3];
    const float* feat     = (const float*)d_in[4];
    const float* W1       = (const float*)d_in[5];
    const float* b1       = (const float*)d_in[6];
    const float* W2       = (const float*)d_in[7];
    const float* b2       = (const float*)d_in[8];
    float* out = (float*)d_out;

    const int E = in_sizes[0];
    const int N = in_sizes[3];

    // workspace layout
    char* ws = (char*)d_ws;
    size_t off = 0;
    int* rp        = (int*)(ws + off);   off += (((size_t)(N + 1) * 4) + 255) & ~(size_t)255;
    float* L1x     = (float*)(ws + off); off += (size_t)N * DD * 4;
    float* Linter  = (float*)(ws + off); off += (size_t)N * DD * 4;
    uint32* featbf = (uint32*)(ws + off); off += (size_t)N * DH * 4;
    uint32* interbf= (uint32*)(ws + off); off += (size_t)N * DH * 4;
    float* WT1     = (float*)(ws + off); off += (size_t)DD * DD * 4;
    float* WT2     = (float*)(ws + off); off += (size_t)DD * DD * 4;
    (void)ws_size; (void)n_in; (void)out_size;

    // 1. row_ptr
    k_row_ptr<<<(N + 1 + 255) / 256, 256, 0, stream>>>(edge_row, rp, N, E);
    // 2. prep: featbf + W transpose
    {
        int work = N * (DD / 4);
        if (work < 2 * DD * DD) work = 2 * DD * DD;
        k_prep<<<(work + 255) / 256, 256, 0, stream>>>(feat, featbf, W1, W2, WT1, WT2, N);
    }
    // 3. SpMM pass 1: L1x (f32), interbf (bf16)
    k_spmm<1><<<(N + 3) / 4, 256, 0, stream>>>(edge_col, edge_val, featbf, rp, featbf, diag,
                                               L1x, interbf, N);
    // 4. SpMM pass 2: Linter (f32)
    k_spmm<2><<<(N + 3) / 4, 256, 0, stream>>>(edge_col, edge_val, interbf, rp, nullptr, nullptr,
                                               Linter, nullptr, N);
    // 5. fused dual GEMM + bias
    k_gemm<<<(N + 63) / 64, 256, 0, stream>>>(L1x, Linter, WT1, WT2, b1, b2, out, N);
}

// Round 3
// 260.020 us; speedup vs baseline: 2.2961x; 1.4441x over previous
//
#include <hip/hip_runtime.h>

#define DD 128   // feature dim
#define DH 64    // bf16-pairs (uint) per row

typedef unsigned int uint32;
typedef __attribute__((ext_vector_type(8))) short short8;
typedef __attribute__((ext_vector_type(4))) float f32x4;

__device__ __forceinline__ uint32 pack_bf16(float a, float b) {
    uint32 ua = __builtin_bit_cast(uint32, a);
    uint32 ub = __builtin_bit_cast(uint32, b);
    ua = (ua + 0x7fffu + ((ua >> 16) & 1u)) >> 16;   // RNE
    ub = (ub + 0x7fffu + ((ub >> 16) & 1u)) >> 16;
    return ua | (ub << 16);
}

__device__ __forceinline__ float bf_lo(uint32 u) { return __builtin_bit_cast(float, u << 16); }
__device__ __forceinline__ float bf_hi(uint32 u) { return __builtin_bit_cast(float, u & 0xffff0000u); }

// ---------------- row_ptr via binary search on sorted edge_row ----------------
__global__ __launch_bounds__(256) void k_row_ptr(const int* __restrict__ row,
                                                 int* __restrict__ rp, int n, int e) {
    int i = blockIdx.x * 256 + threadIdx.x;
    if (i > n) return;
    int lo = 0, hi = e;
    while (lo < hi) { int m = (lo + hi) >> 1; if (row[m] < i) lo = m + 1; else hi = m; }
    rp[i] = lo;
}

// ---------------- prep: feat -> bf16 pairs; W1,W2 -> bf16 (same [j][k] layout) ----------------
__global__ __launch_bounds__(256) void k_prep(const float* __restrict__ feat,
                                              uint32* __restrict__ featbf,
                                              const float* __restrict__ W1,
                                              const float* __restrict__ W2,
                                              uint32* __restrict__ Wb1,
                                              uint32* __restrict__ Wb2, int n) {
    int id = blockIdx.x * 256 + threadIdx.x;
    if (id < n * (DD / 4)) {
        float4 f = ((const float4*)feat)[id];
        uint32 p0 = pack_bf16(f.x, f.y);
        uint32 p1 = pack_bf16(f.z, f.w);
        ((uint2*)featbf)[id] = make_uint2(p0, p1);
    }
    if (id < 2 * DD * DD / 4) {                    // 8192 float4 slots
        int mat = id >> 12, rem = id & 4095;
        float4 wv = ((const float4*)(mat ? W2 : W1))[rem];
        uint2 p;
        p.x = pack_bf16(wv.x, wv.y);
        p.y = pack_bf16(wv.z, wv.w);
        ((uint2*)(mat ? Wb2 : Wb1))[rem] = p;
    }
}

// ---------------- SpMM: one wave per row, lane owns a bf16 pair ----------------
// PASS 1: out1 = L1x = Lx + diag*feat (bf16) ; out2 = inter = Lx*feat (bf16)
// PASS 2: out1 = Linter = L @ inter (bf16)
template <int PASS>
__global__ __launch_bounds__(256) void k_spmm(const int* __restrict__ col,
                                              const float* __restrict__ val,
                                              const uint32* __restrict__ xbf,
                                              const int* __restrict__ rp,
                                              const uint32* __restrict__ featbf,
                                              const float* __restrict__ diag,
                                              uint32* __restrict__ out1,
                                              uint32* __restrict__ out2, int n) {
    int lane = threadIdx.x & 63;
    int row = blockIdx.x * 4 + (threadIdx.x >> 6);
    if (row >= n) return;
    row = __builtin_amdgcn_readfirstlane(row);  // wave-uniform -> scalar loads
    int s = rp[row], eend = rp[row + 1];
    float ax = 0.f, ay = 0.f;
    int e = s;
    for (; e + 8 <= eend; e += 8) {
        int c[8]; float v[8]; uint32 g[8];
#pragma unroll
        for (int u = 0; u < 8; ++u) { c[u] = col[e + u]; v[u] = val[e + u]; }
#pragma unroll
        for (int u = 0; u < 8; ++u) { g[u] = xbf[c[u] * DH + lane]; }
#pragma unroll
        for (int u = 0; u < 8; ++u) {
            ax = fmaf(v[u], bf_lo(g[u]), ax);
            ay = fmaf(v[u], bf_hi(g[u]), ay);
        }
    }
    for (; e < eend; ++e) {
        int c = col[e]; float v = val[e];
        uint32 g = xbf[c * DH + lane];
        ax = fmaf(v, bf_lo(g), ax);
        ay = fmaf(v, bf_hi(g), ay);
    }
    if (PASS == 1) {
        float dg = diag[row];
        uint32 fu = featbf[row * DH + lane];
        float fx = bf_lo(fu), fy = bf_hi(fu);
        out1[row * DH + lane] = pack_bf16(fmaf(dg, fx, ax), fmaf(dg, fy, ay));
        out2[row * DH + lane] = pack_bf16(ax * fx, ay * fy);
    } else {
        out1[row * DH + lane] = pack_bf16(ax, ay);
    }
}

// ---------------- fused dual GEMM via MFMA: out = A@W1^T + B@W2^T + b1 + b2 ----------------
// A,B are bf16 [n][128]; W staged once in LDS (bf16, [j][k] layout, XOR-swizzled).
// 512 threads = 8 waves; block computes 256 rows; wave w owns rows [w*32, w*32+32).
__global__ __launch_bounds__(512, 2) void k_gemm(const uint32* __restrict__ Abf,
                                                 const uint32* __restrict__ Bbf,
                                                 const uint32* __restrict__ Wb1g,
                                                 const uint32* __restrict__ Wb2g,
                                                 const float* __restrict__ b1,
                                                 const float* __restrict__ b2,
                                                 float* __restrict__ out, int n) {
    __shared__ __align__(16) char lds[65536];   // Wb1 @0, Wb2 @32768 (32 KB each)
    int t = threadIdx.x;
    {
        const uint2* s1 = (const uint2*)Wb1g;
        const uint2* s2 = (const uint2*)Wb2g;
#pragma unroll
        for (int u = 0; u < 16; ++u) {
            int id = u * 512 + t;                  // 0..8191 uint2 slots
            int j = id >> 5, kq = id & 31;
            int dst = j * 256 + ((kq * 8) ^ ((j & 7) << 4));
            *(uint2*)(lds + dst) = s1[id];
            *(uint2*)(lds + 32768 + dst) = s2[id];
        }
    }
    __syncthreads();
    int lane = t & 63, w = t >> 6;
    int g = lane >> 4;                             // k-chunk group 0..3
    int rowbase = blockIdx.x * 256 + w * 32;
    int rr = rowbase + (lane & 15);
    int r0 = min(rr, n - 1);
    int r1 = min(rr + 16, n - 1);
    const uint4* A4 = (const uint4*)Abf;           // 16 uint4 per row
    const uint4* B4 = (const uint4*)Bbf;

    f32x4 acc[2][8];
#pragma unroll
    for (int mt = 0; mt < 2; ++mt)
#pragma unroll
        for (int jt = 0; jt < 8; ++jt) acc[mt][jt] = (f32x4){0.f, 0.f, 0.f, 0.f};

    uint4 a0 = A4[(size_t)r0 * 16 + g], a1 = A4[(size_t)r1 * 16 + g];
    uint4 c0 = B4[(size_t)r0 * 16 + g], c1 = B4[(size_t)r1 * 16 + g];
#pragma unroll
    for (int kc = 0; kc < 4; ++kc) {
        uint4 na0, na1, nc0, nc1;
        if (kc < 3) {
            na0 = A4[(size_t)r0 * 16 + (kc + 1) * 4 + g];
            na1 = A4[(size_t)r1 * 16 + (kc + 1) * 4 + g];
            nc0 = B4[(size_t)r0 * 16 + (kc + 1) * 4 + g];
            nc1 = B4[(size_t)r1 * 16 + (kc + 1) * 4 + g];
        }
        short8 fa0 = __builtin_bit_cast(short8, a0);
        short8 fa1 = __builtin_bit_cast(short8, a1);
        short8 fc0 = __builtin_bit_cast(short8, c0);
        short8 fc1 = __builtin_bit_cast(short8, c1);
        int kbase = kc * 64 + g * 16;
#pragma unroll
        for (int jt = 0; jt < 8; ++jt) {
            int j = jt * 16 + (lane & 15);
            int off = j * 256 + (kbase ^ ((j & 7) << 4));
            short8 w1 = *(const short8*)(lds + off);
            short8 w2 = *(const short8*)(lds + 32768 + off);
            acc[0][jt] = __builtin_amdgcn_mfma_f32_16x16x32_bf16(fa0, w1, acc[0][jt], 0, 0, 0);
            acc[0][jt] = __builtin_amdgcn_mfma_f32_16x16x32_bf16(fc0, w2, acc[0][jt], 0, 0, 0);
            acc[1][jt] = __builtin_amdgcn_mfma_f32_16x16x32_bf16(fa1, w1, acc[1][jt], 0, 0, 0);
            acc[1][jt] = __builtin_amdgcn_mfma_f32_16x16x32_bf16(fc1, w2, acc[1][jt], 0, 0, 0);
        }
        a0 = na0; a1 = na1; c0 = nc0; c1 = nc1;
    }
    float bsum[8];
#pragma unroll
    for (int jt = 0; jt < 8; ++jt) {
        int cj = jt * 16 + (lane & 15);
        bsum[jt] = b1[cj] + b2[cj];
    }
#pragma unroll
    for (int mt = 0; mt < 2; ++mt) {
#pragma unroll
        for (int i = 0; i < 4; ++i) {
            int r = rowbase + mt * 16 + g * 4 + i;
            if (r < n) {
                float* orow = out + (size_t)r * DD;
#pragma unroll
                for (int jt = 0; jt < 8; ++jt)
                    orow[jt * 16 + (lane & 15)] = acc[mt][jt][i] + bsum[jt];
            }
        }
    }
}

extern "C" void kernel_launch(void* const* d_in, const int* in_sizes, int n_in,
                              void* d_out, int out_size, void* d_ws, size_t ws_size,
                              hipStream_t stream) {
    const int*   edge_row = (const int*)d_in[0];
    const int*   edge_col = (const int*)d_in[1];
    const float* edge_val = (const float*)d_in[2];
    const float* diag     = (const float*)d_in[3];
    const float* feat     = (const float*)d_in[4];
    const float* W1       = (const float*)d_in[5];
    const float* b1       = (const float*)d_in[6];
    const float* W2       = (const float*)d_in[7];
    const float* b2       = (const float*)d_in[8];
    float* out = (float*)d_out;

    const int E = in_sizes[0];
    const int N = in_sizes[3];

    // workspace layout
    char* ws = (char*)d_ws;
    size_t off = 0;
    int* rp          = (int*)(ws + off);    off += (((size_t)(N + 1) * 4) + 255) & ~(size_t)255;
    uint32* featbf   = (uint32*)(ws + off); off += (size_t)N * DH * 4;
    uint32* interbf  = (uint32*)(ws + off); off += (size_t)N * DH * 4;
    uint32* L1xbf    = (uint32*)(ws + off); off += (size_t)N * DH * 4;
    uint32* Linterbf = (uint32*)(ws + off); off += (size_t)N * DH * 4;
    uint32* Wb1g     = (uint32*)(ws + off); off += (size_t)DD * DH * 4;
    uint32* Wb2g     = (uint32*)(ws + off); off += (size_t)DD * DH * 4;
    (void)ws_size; (void)n_in; (void)out_size;

    // 1. row_ptr
    k_row_ptr<<<(N + 1 + 255) / 256, 256, 0, stream>>>(edge_row, rp, N, E);
    // 2. prep: featbf + W -> bf16
    {
        int work = N * (DD / 4);
        if (work < 2 * DD * DD / 4) work = 2 * DD * DD / 4;
        k_prep<<<(work + 255) / 256, 256, 0, stream>>>(feat, featbf, W1, W2, Wb1g, Wb2g, N);
    }
    // 3. SpMM pass 1: L1xbf, interbf
    k_spmm<1><<<(N + 3) / 4, 256, 0, stream>>>(edge_col, edge_val, featbf, rp, featbf, diag,
                                               L1xbf, interbf, N);
    // 4. SpMM pass 2: Linterbf
    k_spmm<2><<<(N + 3) / 4, 256, 0, stream>>>(edge_col, edge_val, interbf, rp, nullptr, nullptr,
                                               Linterbf, nullptr, N);
    // 5. fused dual GEMM + bias (MFMA)
    k_gemm<<<(N + 255) / 256, 512, 0, stream>>>(L1xbf, Linterbf, Wb1g, Wb2g, b1, b2, out, N);
}

// Round 4
// 193.974 us; speedup vs baseline: 3.0779x; 1.3405x over previous
//
#include <hip/hip_runtime.h>

#define DD 128   // feature dim
#define DH 64    // pairs per row (bf16-pair uints or fp8-pair ushorts)

typedef unsigned int uint32;
typedef unsigned short ushort16;
typedef __attribute__((ext_vector_type(8))) short short8;
typedef __attribute__((ext_vector_type(4))) float f32x4;
typedef __attribute__((ext_vector_type(2))) float f32x2;

__device__ __forceinline__ uint32 pack_bf16(float a, float b) {
    uint32 ua = __builtin_bit_cast(uint32, a);
    uint32 ub = __builtin_bit_cast(uint32, b);
    ua = (ua + 0x7fffu + ((ua >> 16) & 1u)) >> 16;   // RNE
    ub = (ub + 0x7fffu + ((ub >> 16) & 1u)) >> 16;
    return ua | (ub << 16);
}

// ---------------- fp8 e4m3 helpers (hw path on gfx950, sw fallback) ----------------
#if __has_builtin(__builtin_amdgcn_cvt_pk_f32_fp8) && __has_builtin(__builtin_amdgcn_cvt_pk_fp8_f32)
#define FP8_HW 1
#else
#define FP8_HW 0
#endif

__device__ __forceinline__ float2 fp8x2_dec(uint32 u) {
#if FP8_HW
    f32x2 r = __builtin_amdgcn_cvt_pk_f32_fp8(u, false);
    return make_float2(r.x, r.y);
#else
    float2 o;
    uint32 b0 = u & 0xff, b1 = (u >> 8) & 0xff;
    {
        uint32 s = (b0 >> 7) & 1, e = (b0 >> 3) & 15, m = b0 & 7;
        float v = (e == 0) ? ldexpf((float)m, -9) : ldexpf((float)(8 + m), (int)e - 10);
        o.x = s ? -v : v;
    }
    {
        uint32 s = (b1 >> 7) & 1, e = (b1 >> 3) & 15, m = b1 & 7;
        float v = (e == 0) ? ldexpf((float)m, -9) : ldexpf((float)(8 + m), (int)e - 10);
        o.y = s ? -v : v;
    }
    return o;
#endif
}

#if !FP8_HW
__device__ __forceinline__ uint32 fp8_enc1(float x) {
    uint32 u = __builtin_bit_cast(uint32, x);
    uint32 s = (u >> 31) << 7;
    float ax = fabsf(x);
    if (ax >= 448.f) return s | 0x7E;
    if (ax < 0.0009765625f) return s;   // < 2^-10 -> 0
    if (ax >= 0.015625f) {              // normal
        uint32 e = (u >> 23) & 0xFF;
        uint32 m = u & 0x7FFFFF;
        uint32 keep = m >> 20, rest = m & 0xFFFFF;
        keep += (rest > 0x80000u) || (rest == 0x80000u && (keep & 1));
        uint32 ee = e - 127 + 7;
        if (keep == 8) { keep = 0; ee += 1; }
        if (ee > 15 || (ee == 15 && keep > 6)) return s | 0x7E;
        return s | (ee << 3) | keep;
    }
    uint32 ni = (uint32)(ax * 512.f + 0.5f);
    if (ni >= 8) return s | (1u << 3);
    return s | ni;
}
#endif

__device__ __forceinline__ uint32 fp8x2_enc(float a, float b) {
#if FP8_HW
    return __builtin_amdgcn_cvt_pk_fp8_f32(a, b, 0, false) & 0xffffu;
#else
    return fp8_enc1(a) | (fp8_enc1(b) << 8);
#endif
}

__device__ __forceinline__ uint32 fp8x4_enc(float4 f) {
#if FP8_HW
    uint32 w = __builtin_amdgcn_cvt_pk_fp8_f32(f.x, f.y, 0, false);
    w = __builtin_amdgcn_cvt_pk_fp8_f32(f.z, f.w, w, true);
    return w;
#else
    return fp8_enc1(f.x) | (fp8_enc1(f.y) << 8) | (fp8_enc1(f.z) << 16) | (fp8_enc1(f.w) << 24);
#endif
}

// ---------------- row_ptr via binary search on sorted edge_row ----------------
__global__ __launch_bounds__(256) void k_row_ptr(const int* __restrict__ row,
                                                 int* __restrict__ rp, int n, int e) {
    int i = blockIdx.x * 256 + threadIdx.x;
    if (i > n) return;
    int lo = 0, hi = e;
    while (lo < hi) { int m = (lo + hi) >> 1; if (row[m] < i) lo = m + 1; else hi = m; }
    rp[i] = lo;
}

// ---------------- prep: feat -> fp8 (gather copy); W1,W2 -> bf16 ----------------
__global__ __launch_bounds__(256) void k_prep(const float* __restrict__ feat,
                                              uint32* __restrict__ featq,
                                              const float* __restrict__ W1,
                                              const float* __restrict__ W2,
                                              uint32* __restrict__ Wb1,
                                              uint32* __restrict__ Wb2, int n) {
    int id = blockIdx.x * 256 + threadIdx.x;
    if (id < n * (DD / 4)) {
        float4 f = ((const float4*)feat)[id];
        featq[id] = fp8x4_enc(f);
    }
    if (id < 2 * DD * DD / 4) {                    // 8192 float4 slots
        int mat = id >> 12, rem = id & 4095;
        float4 wv = ((const float4*)(mat ? W2 : W1))[rem];
        uint2 p;
        p.x = pack_bf16(wv.x, wv.y);
        p.y = pack_bf16(wv.z, wv.w);
        ((uint2*)(mat ? Wb2 : Wb1))[rem] = p;
    }
}

// ---------------- SpMM: one wave per row, lane owns an fp8 pair (2B gather) ----------------
// PASS 1: out1 = L1x = Lx + diag*feat (bf16) ; out2 = inter = Lx*feat (fp8)
// PASS 2: out1 = Linter = L @ inter (bf16)
template <int PASS>
__global__ __launch_bounds__(256) void k_spmm(const int* __restrict__ col,
                                              const float* __restrict__ val,
                                              const ushort16* __restrict__ xq,
                                              const int* __restrict__ rp,
                                              const float* __restrict__ feat,
                                              const float* __restrict__ diag,
                                              uint32* __restrict__ out1,
                                              ushort16* __restrict__ out2, int n) {
    int lane = threadIdx.x & 63;
    int row = blockIdx.x * 4 + (threadIdx.x >> 6);
    if (row >= n) return;
    row = __builtin_amdgcn_readfirstlane(row);  // wave-uniform -> scalar loads
    int s = rp[row], eend = rp[row + 1];
    float ax = 0.f, ay = 0.f;
    int e = s;
    for (; e + 8 <= eend; e += 8) {
        int c[8]; float v[8]; ushort16 g[8];
#pragma unroll
        for (int u = 0; u < 8; ++u) { c[u] = col[e + u]; v[u] = val[e + u]; }
#pragma unroll
        for (int u = 0; u < 8; ++u) { g[u] = xq[c[u] * DH + lane]; }
#pragma unroll
        for (int u = 0; u < 8; ++u) {
            float2 f = fp8x2_dec(g[u]);
            ax = fmaf(v[u], f.x, ax);
            ay = fmaf(v[u], f.y, ay);
        }
    }
    for (; e < eend; ++e) {
        int c = col[e]; float v = val[e];
        float2 f = fp8x2_dec(xq[c * DH + lane]);
        ax = fmaf(v, f.x, ax);
        ay = fmaf(v, f.y, ay);
    }
    if (PASS == 1) {
        float dg = diag[row];
        float2 f = ((const float2*)feat)[(size_t)row * DH + lane];
        out1[row * DH + lane] = pack_bf16(fmaf(dg, f.x, ax), fmaf(dg, f.y, ay));
        out2[row * DH + lane] = (ushort16)fp8x2_enc(ax * f.x, ay * f.y);
    } else {
        out1[row * DH + lane] = pack_bf16(ax, ay);
    }
}

// ---------------- fused dual GEMM via MFMA: out = A@W1^T + B@W2^T + b1 + b2 ----------------
// A,B are bf16 [n][128]; W staged once in LDS (bf16, [j][k] layout, XOR-swizzled).
// 512 threads = 8 waves; block computes 256 rows; wave w owns rows [w*32, w*32+32).
__global__ __launch_bounds__(512, 2) void k_gemm(const uint32* __restrict__ Abf,
                                                 const uint32* __restrict__ Bbf,
                                                 const uint32* __restrict__ Wb1g,
                                                 const uint32* __restrict__ Wb2g,
                                                 const float* __restrict__ b1,
                                                 const float* __restrict__ b2,
                                                 float* __restrict__ out, int n) {
    __shared__ __align__(16) char lds[65536];   // Wb1 @0, Wb2 @32768 (32 KB each)
    int t = threadIdx.x;
    {
        const uint2* s1 = (const uint2*)Wb1g;
        const uint2* s2 = (const uint2*)Wb2g;
#pragma unroll
        for (int u = 0; u < 16; ++u) {
            int id = u * 512 + t;                  // 0..8191 uint2 slots
            int j = id >> 5, kq = id & 31;
            int dst = j * 256 + ((kq * 8) ^ ((j & 7) << 4));
            *(uint2*)(lds + dst) = s1[id];
            *(uint2*)(lds + 32768 + dst) = s2[id];
        }
    }
    __syncthreads();
    int lane = t & 63, w = t >> 6;
    int g = lane >> 4;                             // k-chunk group 0..3
    int rowbase = blockIdx.x * 256 + w * 32;
    int rr = rowbase + (lane & 15);
    int r0 = min(rr, n - 1);
    int r1 = min(rr + 16, n - 1);
    const uint4* A4 = (const uint4*)Abf;           // 16 uint4 per row
    const uint4* B4 = (const uint4*)Bbf;

    f32x4 acc[2][8];
#pragma unroll
    for (int mt = 0; mt < 2; ++mt)
#pragma unroll
        for (int jt = 0; jt < 8; ++jt) acc[mt][jt] = (f32x4){0.f, 0.f, 0.f, 0.f};

    uint4 a0 = A4[(size_t)r0 * 16 + g], a1 = A4[(size_t)r1 * 16 + g];
    uint4 c0 = B4[(size_t)r0 * 16 + g], c1 = B4[(size_t)r1 * 16 + g];
#pragma unroll
    for (int kc = 0; kc < 4; ++kc) {
        uint4 na0, na1, nc0, nc1;
        if (kc < 3) {
            na0 = A4[(size_t)r0 * 16 + (kc + 1) * 4 + g];
            na1 = A4[(size_t)r1 * 16 + (kc + 1) * 4 + g];
            nc0 = B4[(size_t)r0 * 16 + (kc + 1) * 4 + g];
            nc1 = B4[(size_t)r1 * 16 + (kc + 1) * 4 + g];
        }
        short8 fa0 = __builtin_bit_cast(short8, a0);
        short8 fa1 = __builtin_bit_cast(short8, a1);
        short8 fc0 = __builtin_bit_cast(short8, c0);
        short8 fc1 = __builtin_bit_cast(short8, c1);
        int kbase = kc * 64 + g * 16;
#pragma unroll
        for (int jt = 0; jt < 8; ++jt) {
            int j = jt * 16 + (lane & 15);
            int off = j * 256 + (kbase ^ ((j & 7) << 4));
            short8 w1 = *(const short8*)(lds + off);
            short8 w2 = *(const short8*)(lds + 32768 + off);
            acc[0][jt] = __builtin_amdgcn_mfma_f32_16x16x32_bf16(fa0, w1, acc[0][jt], 0, 0, 0);
            acc[0][jt] = __builtin_amdgcn_mfma_f32_16x16x32_bf16(fc0, w2, acc[0][jt], 0, 0, 0);
            acc[1][jt] = __builtin_amdgcn_mfma_f32_16x16x32_bf16(fa1, w1, acc[1][jt], 0, 0, 0);
            acc[1][jt] = __builtin_amdgcn_mfma_f32_16x16x32_bf16(fc1, w2, acc[1][jt], 0, 0, 0);
        }
        a0 = na0; a1 = na1; c0 = nc0; c1 = nc1;
    }
    float bsum[8];
#pragma unroll
    for (int jt = 0; jt < 8; ++jt) {
        int cj = jt * 16 + (lane & 15);
        bsum[jt] = b1[cj] + b2[cj];
    }
#pragma unroll
    for (int mt = 0; mt < 2; ++mt) {
#pragma unroll
        for (int i = 0; i < 4; ++i) {
            int r = rowbase + mt * 16 + g * 4 + i;
            if (r < n) {
                float* orow = out + (size_t)r * DD;
#pragma unroll
                for (int jt = 0; jt < 8; ++jt)
                    orow[jt * 16 + (lane & 15)] = acc[mt][jt][i] + bsum[jt];
            }
        }
    }
}

extern "C" void kernel_launch(void* const* d_in, const int* in_sizes, int n_in,
                              void* d_out, int out_size, void* d_ws, size_t ws_size,
                              hipStream_t stream) {
    const int*   edge_row = (const int*)d_in[0];
    const int*   edge_col = (const int*)d_in[1];
    const float* edge_val = (const float*)d_in[2];
    const float* diag     = (const float*)d_in[3];
    const float* feat     = (const float*)d_in[4];
    const float* W1       = (const float*)d_in[5];
    const float* b1       = (const float*)d_in[6];
    const float* W2       = (const float*)d_in[7];
    const float* b2       = (const float*)d_in[8];
    float* out = (float*)d_out;

    const int E = in_sizes[0];
    const int N = in_sizes[3];

    // workspace layout
    char* ws = (char*)d_ws;
    size_t off = 0;
    int* rp            = (int*)(ws + off);      off += (((size_t)(N + 1) * 4) + 255) & ~(size_t)255;
    uint32* featq      = (uint32*)(ws + off);   off += (size_t)N * (DD / 4) * 4;   // fp8 x
    uint32* interq     = (uint32*)(ws + off);   off += (size_t)N * (DD / 4) * 4;   // fp8 inter
    uint32* L1xbf      = (uint32*)(ws + off);   off += (size_t)N * DH * 4;
    uint32* Linterbf   = (uint32*)(ws + off);   off += (size_t)N * DH * 4;
    uint32* Wb1g       = (uint32*)(ws + off);   off += (size_t)DD * DH * 4;
    uint32* Wb2g       = (uint32*)(ws + off);   off += (size_t)DD * DH * 4;
    (void)ws_size; (void)n_in; (void)out_size;

    // 1. row_ptr
    k_row_ptr<<<(N + 1 + 255) / 256, 256, 0, stream>>>(edge_row, rp, N, E);
    // 2. prep: feat -> fp8, W -> bf16
    {
        int work = N * (DD / 4);
        if (work < 2 * DD * DD / 4) work = 2 * DD * DD / 4;
        k_prep<<<(work + 255) / 256, 256, 0, stream>>>(feat, featq, W1, W2, Wb1g, Wb2g, N);
    }
    // 3. SpMM pass 1: L1x (bf16), inter (fp8)
    k_spmm<1><<<(N + 3) / 4, 256, 0, stream>>>(edge_col, edge_val, (const ushort16*)featq, rp,
                                               feat, diag, L1xbf, (ushort16*)interq, N);
    // 4. SpMM pass 2: Linter (bf16)
    k_spmm<2><<<(N + 3) / 4, 256, 0, stream>>>(edge_col, edge_val, (const ushort16*)interq, rp,
                                               nullptr, nullptr, Linterbf, nullptr, N);
    // 5. fused dual GEMM + bias (MFMA)
    k_gemm<<<(N + 255) / 256, 512, 0, stream>>>(L1xbf, Linterbf, Wb1g, Wb2g, b1, b2, out, N);
}